// Round 8
// baseline (2137.123 us; speedup 1.0000x reference)
//
#include <hip/hip_runtime.h>
#include <hip/hip_bf16.h>
#include <math.h>

typedef __hip_bfloat16 bf16;
__device__ __forceinline__ float toF(float v){ return v; }
__device__ __forceinline__ float toF(bf16 v){ return __bfloat162float(v); }
__device__ __forceinline__ bf16 f2bf(float v){ return __float2bfloat16(v); }

#define D_    300
#define H_    5
#define NB    64
#define LL    1024
#define KK    64
#define ETXT  2048
#define EIMG  512
#define KP2   1536   // GEMM K: H*D=1500 padded to 48*32
#define APAD  1544   // A_lds row stride in bf16 (1536+8 -> bank shift 4/row)

typedef __attribute__((ext_vector_type(8))) short short8;
typedef __attribute__((ext_vector_type(4))) float f32x4;

// Mask storage modes: 0 = 4-byte word, 1 = 2-byte, 2 = 1-byte (bool), 3 = 8-byte.
__device__ __forceinline__ int read_mask(const void* p, int i, int mode) {
  switch (mode) {
    case 1: return ((const unsigned short*)p)[i] != 0;
    case 2: return ((const unsigned char*)p)[i] != 0;
    case 3: { const unsigned int* w = (const unsigned int*)p;
              return (w[2*i] | w[2*i+1]) != 0; }
    default: return ((const unsigned int*)p)[i] != 0;
  }
}

__global__ void k_detect(const unsigned int* __restrict__ w, int nwords,
                         int* __restrict__ mode) {
  __shared__ unsigned int se[256], so[256];
  unsigned int oe = 0, oo = 0;
  for (int i = threadIdx.x; i < nwords; i += 256) {
    unsigned int v = w[i];
    if (i & 1) oo |= v; else oe |= v;
  }
  se[threadIdx.x] = oe; so[threadIdx.x] = oo;
  __syncthreads();
  for (int s = 128; s; s >>= 1) {
    if (threadIdx.x < s) { se[threadIdx.x] |= se[threadIdx.x+s]; so[threadIdx.x] |= so[threadIdx.x+s]; }
    __syncthreads();
  }
  if (threadIdx.x == 0) {
    unsigned int O = se[0] | so[0];
    int m = 0;
    if (O == 0u) m = 0;
    else if ((O & 0xFFFFu) == 0x3F80u) m = 1;
    else if ((O >> 16) == 0x3F80u && (O & 0xFFFFu) == 0u) m = 0;
    else if ((O >> 16) == 0x3FF0u) m = 3;
    else if (O <= 1u) m = (so[0] == 0u && se[0] != 0u) ? 3 : 0;
    else if ((O & 0xFEFEFEFEu) == 0u) m = 2;
    mode[0] = m;
  }
}

__global__ void k_zero(float* __restrict__ a, float* __restrict__ b,
                       float* __restrict__ cc, int n) {
  int i = blockIdx.x * 256 + threadIdx.x;
  if (i < n) { a[i] = 0.f; b[i] = 0.f; cc[i] = 0.f; }
}

__device__ __forceinline__ float clamp_logit(float v) {
  if (!(v > -1e30f)) v = -1e30f;
  if (v > 1e30f) v = 1e30f;
  return v;
}

// ---------------- CSR build: one block per graph ----------------
__global__ __launch_bounds__(256) void k_csr(const int* __restrict__ edges, int estride,
                                             int E, int nodes,
                                             int* __restrict__ csr, int* __restrict__ off) {
  int g = blockIdx.x;
  const int* src = edges + (size_t)g * estride;
  const int* dst = src + E;
  __shared__ int cnt[1024];
  __shared__ int pos[1024];
  __shared__ int bsum[256];
  int tid = threadIdx.x;
  for (int i = tid; i < nodes; i += 256) cnt[i] = 0;
  __syncthreads();
  for (int e = tid; e < E; e += 256) atomicAdd(&cnt[dst[e]], 1);
  __syncthreads();
  int per = (nodes + 255) / 256;
  int s = 0;
  for (int k = 0; k < per; ++k) { int i = tid * per + k; if (i < nodes) s += cnt[i]; }
  bsum[tid] = s;
  __syncthreads();
  if (tid == 0) { int a = 0; for (int i = 0; i < 256; ++i) { int t = bsum[i]; bsum[i] = a; a += t; } }
  __syncthreads();
  s = bsum[tid];
  for (int k = 0; k < per; ++k) {
    int i = tid * per + k;
    if (i < nodes) { pos[i] = s; int t = cnt[i]; cnt[i] = s; s += t; }
  }
  __syncthreads();
  for (int i = tid; i < nodes; i += 256) off[(size_t)g * (nodes + 1) + i] = cnt[i];
  if (tid == 0) off[(size_t)g * (nodes + 1) + nodes] = E;
  for (int e = tid; e < E; e += 256) {
    int p = atomicAdd(&pos[dst[e]], 1);
    csr[(size_t)g * E + p] = src[e];
  }
}

// ---------------- pa_token logits (wave per row) ----------------
__global__ void k_logits_tok(const float* __restrict__ x, const float* __restrict__ w,
                             const float* __restrict__ b, const void* __restrict__ mask,
                             const int* __restrict__ mmode,
                             float* __restrict__ logits, int rows) {
  int row = blockIdx.x * blockDim.y + threadIdx.y;
  if (row >= rows) return;
  int lane = threadIdx.x;
  const float* xp = x + (size_t)row * D_;
  float acc = 0.f;
  for (int d = lane; d < D_; d += 64) acc += xp[d] * w[d];
#pragma unroll
  for (int off = 32; off; off >>= 1) acc += __shfl_down(acc, off);
  if (lane == 0) {
    float v = clamp_logit(acc + b[0]);
    if (read_mask(mask, row, mmode[0])) v = -INFINITY;
    logits[row] = v;
  }
}

// ---------------- logit for the c-row (l == LL) of lg2 ----------------
__global__ void k_logits_c(const float* __restrict__ c, const float* __restrict__ w,
                           const float* __restrict__ b, const void* __restrict__ mask,
                           const int* __restrict__ mmode, float* __restrict__ lg2) {
  int n = blockIdx.x * blockDim.y + threadIdx.y;
  if (n >= NB) return;
  int lane = threadIdx.x;
  const float* cp = c + (size_t)n * D_;
  float acc = 0.f;
  for (int d = lane; d < D_; d += 64) acc += cp[d] * w[d];
#pragma unroll
  for (int off = 32; off; off >>= 1) acc += __shfl_down(acc, off);
  if (lane == 0) {
    float v = clamp_logit(acc + b[0]);
    if (read_mask(mask, n * (LL + 1) + LL, mmode[0])) v = -INFINITY;
    lg2[n * (LL + 1) + LL] = v;
  }
}

// ---------------- in-place softmax probs over a row of `len` ----------------
__global__ __launch_bounds__(256) void k_probs(float* __restrict__ lg, int len) {
  int n = blockIdx.x, tid = threadIdx.x;
  __shared__ float w[LL + 1];
  __shared__ float red[4];
  __shared__ float stat;
  float m = -INFINITY;
  for (int l = tid; l < len; l += 256) { float v = lg[n * len + l]; w[l] = v; m = fmaxf(m, v); }
#pragma unroll
  for (int off = 32; off; off >>= 1) m = fmaxf(m, __shfl_down(m, off));
  if ((tid & 63) == 0) red[tid >> 6] = m;
  __syncthreads();
  if (tid == 0) stat = fmaxf(fmaxf(red[0], red[1]), fmaxf(red[2], red[3]));
  __syncthreads();
  float M = stat;
  if (!(M > -INFINITY && M < INFINITY)) M = 0.f;
  float s = 0.f;
  for (int l = tid; l < len; l += 256) { float p = __expf(w[l] - M); w[l] = p; s += p; }
#pragma unroll
  for (int off = 32; off; off >>= 1) s += __shfl_down(s, off);
  __syncthreads();
  if ((tid & 63) == 0) red[tid >> 6] = s;
  __syncthreads();
  if (tid == 0) stat = red[0] + red[1] + red[2] + red[3];
  __syncthreads();
  float inv = (stat > 0.f) ? 1.f / stat : 0.f;
  for (int l = tid; l < len; l += 256) lg[n * len + l] = w[l] * inv;
}

// ---------------- split-L partial sums: c += t2*score, u1 += p1*t2 ----------------
__global__ __launch_bounds__(128) void k_cu1(const float* __restrict__ t2,
                                             const float* __restrict__ score,
                                             const float* __restrict__ probs,
                                             float* __restrict__ c, float* __restrict__ u1) {
  int n = blockIdx.x, lc = blockIdx.y, tid = threadIdx.x;
  float aC[3] = {0.f, 0.f, 0.f}, aU[3] = {0.f, 0.f, 0.f};
  const float* base = t2 + (size_t)n * LL * D_;
  const float* sbase = score + (size_t)n * LL * D_;
  for (int l = lc * 128; l < lc * 128 + 128; ++l) {
    float w = probs[n * LL + l];
    const float* tp = base + (size_t)l * D_;
    const float* sp = sbase + (size_t)l * D_;
#pragma unroll
    for (int t = 0; t < 3; ++t) {
      int d = tid + t * 128;
      if (d < D_) { float tv = tp[d]; aC[t] += tv * sp[d]; aU[t] += w * tv; }
    }
  }
#pragma unroll
  for (int t = 0; t < 3; ++t) {
    int d = tid + t * 128;
    if (d < D_) { atomicAdd(c + n * D_ + d, aC[t]); atomicAdd(u1 + n * D_ + d, aU[t]); }
  }
}

// ---------------- split-L partial sums: u2 += p2*X (l < L only) ----------------
__global__ __launch_bounds__(128) void k_u2(const bf16* __restrict__ X,
                                            const float* __restrict__ probs2,
                                            float* __restrict__ u2) {
  int n = blockIdx.x, lc = blockIdx.y, tid = threadIdx.x;
  float aU[3] = {0.f, 0.f, 0.f};
  const bf16* base = X + (size_t)n * LL * D_;
  for (int l = lc * 128; l < lc * 128 + 128; ++l) {
    float w = probs2[n * (LL + 1) + l];
    const bf16* xp = base + (size_t)l * D_;
#pragma unroll
    for (int t = 0; t < 3; ++t) {
      int d = tid + t * 128;
      if (d < D_) aU[t] += w * toF(xp[d]);
    }
  }
#pragma unroll
  for (int t = 0; t < 3; ++t) {
    int d = tid + t * 128;
    if (d < D_) atomicAdd(u2 + n * D_ + d, aU[t]);
  }
}

// ---------------- fused: pack W into Bp2 (transposed bf16) + wvec dots ----------------
__global__ void k_prep(const float* __restrict__ W, const float* __restrict__ att_src,
                       const float* __restrict__ att_dst, bf16* __restrict__ Bp2,
                       float* __restrict__ wsrc, float* __restrict__ wdst) {
  int idx = blockIdx.x * 256 + threadIdx.x;
  if (idx < 320 * KP2) {
    int n = idx / KP2, k = idx - n * KP2;
    float v = 0.f;
    if (n < D_ && k < H_ * D_) {
      int h = k / D_, di = k - h * D_;
      v = W[(size_t)di * (H_ * D_) + h * D_ + n];
    }
    Bp2[idx] = f2bf(v);
  } else {
    int r2 = idx - 320 * KP2;
    if (r2 < 2 * H_ * D_) {
      int s = r2 / (H_ * D_);
      int r = r2 % (H_ * D_);
      int h = r / D_, d = r % D_;
      const float* att = (s ? att_dst : att_src) + h * D_;
      const float* Wp = W + (size_t)d * H_ * D_ + h * D_;
      float acc = 0.f;
      for (int e = 0; e < D_; ++e) acc += Wp[e] * att[e];
      (s ? wdst : wsrc)[h * D_ + d] = acc;
    }
  }
}

// ---------------- a_src/a_dst[row,h] = x[row,:] . wvec[h,:] ----------------
template <typename T>
__global__ void k_asrc(const T* __restrict__ x, const float* __restrict__ wsrc,
                       const float* __restrict__ wdst, float* __restrict__ a_src,
                       float* __restrict__ a_dst, int rows) {
  int row = blockIdx.x * blockDim.y + threadIdx.y;
  if (row >= rows) return;
  int lane = threadIdx.x;
  const T* xp = x + (size_t)row * D_;
  float xr[5];
#pragma unroll
  for (int i = 0; i < 5; ++i) { int d = lane + 64 * i; xr[i] = (d < D_) ? toF(xp[d]) : 0.f; }
#pragma unroll
  for (int hh = 0; hh < H_; ++hh) {
    float as = 0.f, ad = 0.f;
#pragma unroll
    for (int i = 0; i < 5; ++i) {
      int d = lane + 64 * i;
      if (d < D_) { as += xr[i] * wsrc[hh * D_ + d]; ad += xr[i] * wdst[hh * D_ + d]; }
    }
#pragma unroll
    for (int off = 32; off; off >>= 1) { as += __shfl_down(as, off); ad += __shfl_down(ad, off); }
    if (lane == 0) { a_src[(size_t)row * H_ + hh] = as; a_dst[(size_t)row * H_ + hh] = ad; }
  }
}

// ================= fused GAT layer: agg(LDS) + MFMA GEMM + LN (+np logits) =================
// Block: 256 thr (4 waves), 32 node-rows. Build phase: each wave aggregates 8 nodes'
// alpha-weighted x rows into A_lds (bf16, 1544-stride). GEMM: barrier-free K-loop,
// B fragments loaded to registers with 1-iter prefetch. Epilogue: cross-wave LN.
template <typename T>
__global__ __launch_bounds__(256) void k_gat(
    const T* __restrict__ x, const float* __restrict__ a_src, const float* __restrict__ a_dst,
    const int* __restrict__ csr, const int* __restrict__ off, int E, int nodes, int per_graph,
    const bf16* __restrict__ Bp2,
    const float* __restrict__ bias, const float* __restrict__ lng, const float* __restrict__ lnb,
    const void* __restrict__ gmask, const int* __restrict__ mmode,
    const float* __restrict__ w2, const float* __restrict__ b2, const void* __restrict__ npm,
    float* __restrict__ lg2, bf16* __restrict__ Xout) {
  __shared__ bf16 A[32][APAD];   // 98816 B
  int tid = threadIdx.x;
  int wave = tid >> 6, lane = tid & 63;
  int cl = lane & 15, q = lane >> 4;
  int n0 = blockIdx.x * 32;
  {
    uint4 z = {0, 0, 0, 0};
    uint4* ap = (uint4*)&A[0][0];
    for (int i = tid; i < 32 * APAD / 8; i += 256) ap[i] = z;
  }
  __syncthreads();
  int mode = mmode[0];
  // ---- build phase: 8 nodes per wave ----
  for (int t = 0; t < 8; ++t) {
    int nl = wave * 8 + t;
    int row = n0 + nl;
    int g = row / nodes, node = row - g * nodes;
    int gg = per_graph ? g : 0;
    int o0 = off[(size_t)gg * (nodes + 1) + node];
    int deg = off[(size_t)gg * (nodes + 1) + node + 1] - o0;
    if (deg > 128) deg = 128;
    int s1 = (lane < deg) ? csr[(size_t)gg * E + o0 + lane] : 0;
    int s2 = (lane + 64 < deg) ? csr[(size_t)gg * E + o0 + lane + 64] : 0;
    float p1[H_], p2[H_];
    const float* adp = a_dst + (size_t)row * H_;
#pragma unroll
    for (int h = 0; h < H_; ++h) {
      float ah = adp[h];
      float v1 = -INFINITY, v2 = -INFINITY;
      if (lane < deg)      { float v = a_src[((size_t)g * nodes + s1) * H_ + h] + ah; v1 = v > 0.f ? v : 0.2f * v; }
      if (lane + 64 < deg) { float v = a_src[((size_t)g * nodes + s2) * H_ + h] + ah; v2 = v > 0.f ? v : 0.2f * v; }
      float m = fmaxf(v1, v2);
#pragma unroll
      for (int o = 1; o < 64; o <<= 1) m = fmaxf(m, __shfl_xor(m, o));
      float e1 = (lane < deg) ? __expf(v1 - m) : 0.f;
      float e2 = (lane + 64 < deg) ? __expf(v2 - m) : 0.f;
      float s = e1 + e2;
#pragma unroll
      for (int o = 1; o < 64; o <<= 1) s += __shfl_xor(s, o);
      float inv = 1.f / (s + 1e-16f);
      p1[h] = e1 * inv; p2[h] = e2 * inv;
    }
    float acc[5][H_];
#pragma unroll
    for (int k = 0; k < 5; ++k)
#pragma unroll
      for (int h = 0; h < H_; ++h) acc[k][h] = 0.f;
    int d1 = deg < 64 ? deg : 64;
    for (int e = 0; e < d1; ++e) {
      int se = __shfl(s1, e);
      float ah[H_];
#pragma unroll
      for (int h = 0; h < H_; ++h) ah[h] = __shfl(p1[h], e);
      const T* xp = x + ((size_t)g * nodes + se) * D_;
#pragma unroll
      for (int k = 0; k < 5; ++k) {
        int d = lane + 64 * k;
        if (d < D_) {
          float xv = toF(xp[d]);
#pragma unroll
          for (int h = 0; h < H_; ++h) acc[k][h] += ah[h] * xv;
        }
      }
    }
    for (int e = 0; e < deg - 64; ++e) {
      int se = __shfl(s2, e);
      float ah[H_];
#pragma unroll
      for (int h = 0; h < H_; ++h) ah[h] = __shfl(p2[h], e);
      const T* xp = x + ((size_t)g * nodes + se) * D_;
#pragma unroll
      for (int k = 0; k < 5; ++k) {
        int d = lane + 64 * k;
        if (d < D_) {
          float xv = toF(xp[d]);
#pragma unroll
          for (int h = 0; h < H_; ++h) acc[k][h] += ah[h] * xv;
        }
      }
    }
#pragma unroll
    for (int k = 0; k < 5; ++k) {
      int d = lane + 64 * k;
      if (d < D_) {
#pragma unroll
        for (int h = 0; h < H_; ++h) A[nl][h * D_ + d] = f2bf(acc[k][h]);
      }
    }
  }
  __syncthreads();
  // ---- GEMM phase: barrier-free K-loop, B in regs with prefetch ----
  int wc = wave * 80;
  const bf16* gb[5];
#pragma unroll
  for (int j = 0; j < 5; ++j) gb[j] = Bp2 + (size_t)(wc + j * 16 + cl) * KP2 + q * 8;
  f32x4 acc2[2][5] = {};
  short8 bcur[5], bnxt[5];
#pragma unroll
  for (int j = 0; j < 5; ++j) bcur[j] = *(const short8*)gb[j];
  for (int it = 0; it < 48; ++it) {
    if (it < 47) {
      int kn = (it + 1) * 32;
#pragma unroll
      for (int j = 0; j < 5; ++j) bnxt[j] = *(const short8*)(gb[j] + kn);
    }
    int ka = it * 32 + q * 8;
    short8 a0 = *(const short8*)&A[cl][ka];
    short8 a1 = *(const short8*)&A[16 + cl][ka];
#pragma unroll
    for (int j = 0; j < 5; ++j) {
      acc2[0][j] = __builtin_amdgcn_mfma_f32_16x16x32_bf16(a0, bcur[j], acc2[0][j], 0, 0, 0);
      acc2[1][j] = __builtin_amdgcn_mfma_f32_16x16x32_bf16(a1, bcur[j], acc2[1][j], 0, 0, 0);
    }
#pragma unroll
    for (int j = 0; j < 5; ++j) bcur[j] = bnxt[j];
  }
  __syncthreads();
  // ---- epilogue: cross-wave LN (+ fused np-logits) ----
  float* sred = (float*)&A[0][0];   // [32][4]
  float* qred = sred + 128;
  float* lred = qred + 128;
#pragma unroll
  for (int i = 0; i < 2; ++i) {
#pragma unroll
    for (int r = 0; r < 4; ++r) {
      int lrow = i * 16 + q * 4 + r;
      int row = n0 + lrow;
      int mk = gmask ? read_mask(gmask, row / nodes, mode) : 0;
      float s = 0.f, sq = 0.f;
#pragma unroll
      for (int j = 0; j < 5; ++j) {
        int col = wc + j * 16 + cl;
        float v = 0.f;
        if (col < D_) {
          v = acc2[i][j][r] * 0.2f + bias[col];
          if (mk) v = 0.f;
          v = fmaxf(v, 0.f);
        }
        s += v; sq += v * v;
      }
#pragma unroll
      for (int o = 1; o < 16; o <<= 1) { s += __shfl_xor(s, o); sq += __shfl_xor(sq, o); }
      if (cl == 0) { sred[lrow * 4 + wave] = s; qred[lrow * 4 + wave] = sq; }
    }
  }
  __syncthreads();
#pragma unroll
  for (int i = 0; i < 2; ++i) {
#pragma unroll
    for (int r = 0; r < 4; ++r) {
      int lrow = i * 16 + q * 4 + r;
      int row = n0 + lrow;
      float s = sred[lrow * 4 + 0] + sred[lrow * 4 + 1] + sred[lrow * 4 + 2] + sred[lrow * 4 + 3];
      float sq = qred[lrow * 4 + 0] + qred[lrow * 4 + 1] + qred[lrow * 4 + 2] + qred[lrow * 4 + 3];
      int mk = gmask ? read_mask(gmask, row / nodes, mode) : 0;
      float mu = s * (1.f / 300.f);
      float var = fmaxf(sq * (1.f / 300.f) - mu * mu, 0.f);
      float rstd = rsqrtf(var + 1e-5f);
      float ls = 0.f;
#pragma unroll
      for (int j = 0; j < 5; ++j) {
        int col = wc + j * 16 + cl;
        if (col < D_) {
          float v = acc2[i][j][r] * 0.2f + bias[col];
          if (mk) v = 0.f;
          v = fmaxf(v, 0.f);
          float o2 = (v - mu) * rstd * lng[col] + lnb[col];
          Xout[(size_t)row * D_ + col] = f2bf(o2);
          if (w2) ls += o2 * w2[col];
        }
      }
      if (w2) {
#pragma unroll
        for (int o = 1; o < 16; o <<= 1) ls += __shfl_xor(ls, o);
        if (cl == 0) lred[lrow * 4 + wave] = ls;
      }
    }
  }
  if (w2) {
    __syncthreads();
    if (tid < 32) {
      int row = n0 + tid;
      float tot = lred[tid * 4 + 0] + lred[tid * 4 + 1] + lred[tid * 4 + 2] + lred[tid * 4 + 3];
      float v = clamp_logit(tot + b2[0]);
      int g = row / nodes, l = row - g * nodes;
      if (read_mask(npm, g * (nodes + 1) + l, mode)) v = -INFINITY;
      lg2[g * (nodes + 1) + l] = v;
    }
  }
}

// ---------------- final: out[n,k]=a1, out[n,K+k]=a2 ----------------
__global__ void k_out(const float* __restrict__ u1, const float* __restrict__ u2,
                      const float* __restrict__ c, const float* __restrict__ probs2,
                      const float* __restrict__ v2, const bf16* __restrict__ v3,
                      float* __restrict__ out) {
  int idx = blockIdx.x * blockDim.y + threadIdx.y;
  if (idx >= NB * KK) return;
  int n = idx / KK, k = idx - n * KK;
  int lane = threadIdx.x;
  const float* ap = v2 + (size_t)idx * D_;
  const bf16* bp = v3 + (size_t)idx * D_;
  const float* u1p = u1 + n * D_;
  const float* u2p = u2 + n * D_;
  const float* cp = c + n * D_;
  float p2L = probs2[n * (LL + 1) + LL];
  float a1 = 0.f, a2 = 0.f;
  for (int d = lane; d < D_; d += 64) {
    a1 += u1p[d] * ap[d];
    a2 += (u2p[d] + p2L * cp[d]) * toF(bp[d]);
  }
#pragma unroll
  for (int off = 32; off; off >>= 1) { a1 += __shfl_down(a1, off); a2 += __shfl_down(a2, off); }
  if (lane == 0) {
    const float scale = 0.05773502691896258f;  // 1/sqrt(300)
    out[(size_t)n * 2 * KK + k] = a1 * scale;
    out[(size_t)n * 2 * KK + KK + k] = a2 * scale;
  }
}

extern "C" void kernel_launch(void* const* d_in, const int* in_sizes, int n_in,
                              void* d_out, int out_size, void* d_ws, size_t ws_size,
                              hipStream_t stream) {
  const float* t2    = (const float*)d_in[0];
  const float* v2    = (const float*)d_in[1];
  const float* score = (const float*)d_in[2];
  const int*   eidx  = (const int*)d_in[3];
  const void*  gmask = d_in[4];
  const void*  kpm   = d_in[5];
  const void*  npm   = d_in[6];
  const int*   iedge = (const int*)d_in[7];
  const float* txtW  = (const float*)d_in[8];
  const float* txtAs = (const float*)d_in[9];
  const float* txtAd = (const float*)d_in[10];
  const float* txtB  = (const float*)d_in[11];
  const float* imgW  = (const float*)d_in[12];
  const float* imgAs = (const float*)d_in[13];
  const float* imgAd = (const float*)d_in[14];
  const float* imgB  = (const float*)d_in[15];
  const float* w1    = (const float*)d_in[16];
  const float* b1    = (const float*)d_in[17];
  const float* w2    = (const float*)d_in[18];
  const float* b2    = (const float*)d_in[19];
  const float* lng   = (const float*)d_in[20];
  const float* lnb   = (const float*)d_in[21];
  float* out = (float*)d_out;

  char* ws = (char*)d_ws;
  size_t off = 0;
  auto alloc = [&](size_t bytes) -> char* {
    char* p = ws + off;
    off += (bytes + 511) & ~(size_t)511;
    return p;
  };
  int*   mmode = (int*)alloc(64);
  float* c    = (float*)alloc((size_t)NB * D_ * 4);
  float* u1   = (float*)alloc((size_t)NB * D_ * 4);
  float* u2   = (float*)alloc((size_t)NB * D_ * 4);
  float* lg1  = (float*)alloc((size_t)NB * LL * 4);
  float* lg2  = (float*)alloc((size_t)NB * (LL + 1) * 4);
  float* wsrc = (float*)alloc((size_t)H_ * D_ * 4);
  float* wdst = (float*)alloc((size_t)H_ * D_ * 4);
  float* asrc = (float*)alloc((size_t)NB * LL * H_ * 4);
  float* adst = (float*)alloc((size_t)NB * LL * H_ * 4);
  int* csrT   = (int*)alloc((size_t)NB * ETXT * 4);
  int* offT   = (int*)alloc((size_t)NB * (LL + 1) * 4);
  int* csrI   = (int*)alloc((size_t)EIMG * 4);
  int* offI   = (int*)alloc((size_t)(KK + 1) * 4);
  bf16* X1  = (bf16*)alloc((size_t)NB * LL * D_ * 2);
  bf16* X2  = (bf16*)alloc((size_t)NB * LL * D_ * 2);
  bf16* V1  = (bf16*)alloc((size_t)NB * KK * D_ * 2);
  bf16* V2  = (bf16*)alloc((size_t)NB * KK * D_ * 2);
  bf16* Bp2 = (bf16*)alloc((size_t)320 * KP2 * 2);

  dim3 b64x4(64, 4);
  int prep_grid = (320 * KP2 + 2 * H_ * D_ + 255) / 256;
  int Mt = NB * LL;   // txt rows
  int Mi = NB * KK;   // img rows

  k_detect<<<1, 256, 0, stream>>>((const unsigned int*)kpm, NB * LL / 4, mmode);
  k_zero<<<(NB * D_ + 255) / 256, 256, 0, stream>>>(c, u1, u2, NB * D_);
  k_csr<<<NB, 256, 0, stream>>>(eidx, 2 * ETXT, ETXT, LL, csrT, offT);
  k_csr<<<1, 256, 0, stream>>>(iedge, 0, EIMG, KK, csrI, offI);

  // phase 0: pa_token probs; c + u1 partial sums
  k_logits_tok<<<(Mt + 3) / 4, b64x4, 0, stream>>>(t2, w1, b1, kpm, mmode, lg1, Mt);
  k_probs<<<NB, 256, 0, stream>>>(lg1, LL);
  k_cu1<<<dim3(NB, LL / 128), 128, 0, stream>>>(t2, score, lg1, c, u1);

  // text GAT layer 0: t2 -> X1
  k_prep<<<prep_grid, 256, 0, stream>>>(txtW, txtAs, txtAd, Bp2, wsrc, wdst);
  k_asrc<float><<<(Mt + 3) / 4, b64x4, 0, stream>>>(t2, wsrc, wdst, asrc, adst, Mt);
  k_gat<float><<<Mt / 32, 256, 0, stream>>>(
      t2, asrc, adst, csrT, offT, ETXT, LL, 1, Bp2, txtB, lng, lnb,
      gmask, mmode, nullptr, nullptr, nullptr, nullptr, X1);

  // text GAT layer 1: X1 -> X2 (+ fused pa_np logits into lg2)
  k_prep<<<prep_grid, 256, 0, stream>>>(txtW + (size_t)D_ * H_ * D_,
                                        txtAs + H_ * D_, txtAd + H_ * D_, Bp2, wsrc, wdst);
  k_asrc<bf16><<<(Mt + 3) / 4, b64x4, 0, stream>>>(X1, wsrc, wdst, asrc, adst, Mt);
  k_gat<bf16><<<Mt / 32, 256, 0, stream>>>(
      X1, asrc, adst, csrT, offT, ETXT, LL, 1, Bp2, txtB + D_, lng, lnb,
      gmask, mmode, w2, b2, npm, lg2, X2);

  // image GAT layer 0: v2 -> V1
  k_prep<<<prep_grid, 256, 0, stream>>>(imgW, imgAs, imgAd, Bp2, wsrc, wdst);
  k_asrc<float><<<(Mi + 3) / 4, b64x4, 0, stream>>>(v2, wsrc, wdst, asrc, adst, Mi);
  k_gat<float><<<Mi / 32, 256, 0, stream>>>(
      v2, asrc, adst, csrI, offI, EIMG, KK, 0, Bp2, imgB, lng, lnb,
      nullptr, mmode, nullptr, nullptr, nullptr, nullptr, V1);

  // image GAT layer 1: V1 -> V2
  k_prep<<<prep_grid, 256, 0, stream>>>(imgW + (size_t)D_ * H_ * D_,
                                        imgAs + H_ * D_, imgAd + H_ * D_, Bp2, wsrc, wdst);
  k_asrc<bf16><<<(Mi + 3) / 4, b64x4, 0, stream>>>(V1, wsrc, wdst, asrc, adst, Mi);
  k_gat<bf16><<<Mi / 32, 256, 0, stream>>>(
      V1, asrc, adst, csrI, offI, EIMG, KK, 0, Bp2, imgB + D_, lng, lnb,
      nullptr, mmode, nullptr, nullptr, nullptr, nullptr, V2);

  // epilogue: c-row logit, pa_np probs, u2 partial sums, final outputs
  k_logits_c<<<(NB + 3) / 4, b64x4, 0, stream>>>(c, w2, b2, npm, mmode, lg2);
  k_probs<<<NB, 256, 0, stream>>>(lg2, LL + 1);
  k_u2<<<dim3(NB, LL / 128), 128, 0, stream>>>(X2, lg2, u2);
  k_out<<<(NB * KK + 3) / 4, b64x4, 0, stream>>>(u1, u2, c, lg2, v2, V2, out);
}

// Round 9
// 1774.711 us; speedup vs baseline: 1.2042x; 1.2042x over previous
//
#include <hip/hip_runtime.h>
#include <hip/hip_bf16.h>
#include <math.h>

typedef __hip_bfloat16 bf16;
__device__ __forceinline__ float toF(float v){ return v; }
__device__ __forceinline__ float toF(bf16 v){ return __bfloat162float(v); }
__device__ __forceinline__ bf16 f2bf(float v){ return __float2bfloat16(v); }

#define D_    300
#define H_    5
#define NB    64
#define LL    1024
#define KK    64
#define ETXT  2048
#define EIMG  512
#define MAXDEG 128
#define KP2   1536   // GEMM K: H*D=1500 padded to 48*32

typedef __attribute__((ext_vector_type(8))) short short8;
typedef __attribute__((ext_vector_type(4))) float f32x4;

// Mask storage modes: 0 = 4-byte word, 1 = 2-byte, 2 = 1-byte (bool), 3 = 8-byte.
__device__ __forceinline__ int read_mask(const void* p, int i, int mode) {
  switch (mode) {
    case 1: return ((const unsigned short*)p)[i] != 0;
    case 2: return ((const unsigned char*)p)[i] != 0;
    case 3: { const unsigned int* w = (const unsigned int*)p;
              return (w[2*i] | w[2*i+1]) != 0; }
    default: return ((const unsigned int*)p)[i] != 0;
  }
}

__device__ __forceinline__ float clamp_logit(float v) {
  if (!(v > -1e30f)) v = -1e30f;
  if (v > 1e30f) v = 1e30f;
  return v;
}

// ---------------- init: mask detect (block 0) + CSR txt (1..64) + CSR img (65) ----------------
__global__ __launch_bounds__(256) void k_init(
    const unsigned int* __restrict__ kpmw, int nwords, int* __restrict__ mode,
    const int* __restrict__ eidx, const int* __restrict__ iedge,
    int* __restrict__ csrT, int* __restrict__ offT,
    int* __restrict__ csrI, int* __restrict__ offI) {
  __shared__ int cnt[1024];
  __shared__ int pos[1024];
  __shared__ int bsum[256];
  int b = blockIdx.x, tid = threadIdx.x;
  if (b == 0) {
    unsigned int* se = (unsigned int*)cnt;
    unsigned int* so = (unsigned int*)pos;
    unsigned int oe = 0, oo = 0;
    for (int i = tid; i < nwords; i += 256) {
      unsigned int v = kpmw[i];
      if (i & 1) oo |= v; else oe |= v;
    }
    se[tid] = oe; so[tid] = oo;
    __syncthreads();
    for (int s = 128; s; s >>= 1) {
      if (tid < s) { se[tid] |= se[tid+s]; so[tid] |= so[tid+s]; }
      __syncthreads();
    }
    if (tid == 0) {
      unsigned int O = se[0] | so[0];
      int m = 0;
      if (O == 0u) m = 0;
      else if ((O & 0xFFFFu) == 0x3F80u) m = 1;
      else if ((O >> 16) == 0x3F80u && (O & 0xFFFFu) == 0u) m = 0;
      else if ((O >> 16) == 0x3FF0u) m = 3;
      else if (O <= 1u) m = (so[0] == 0u && se[0] != 0u) ? 3 : 0;
      else if ((O & 0xFEFEFEFEu) == 0u) m = 2;
      mode[0] = m;
    }
    return;
  }
  // CSR build
  int g, estride, E, nodes;
  const int* edges;
  int* csr; int* off;
  if (b <= NB) { g = b - 1; edges = eidx; estride = 2 * ETXT; E = ETXT; nodes = LL; csr = csrT; off = offT; }
  else        { g = 0;     edges = iedge; estride = 0;       E = EIMG; nodes = KK; csr = csrI; off = offI; }
  const int* src = edges + (size_t)g * estride;
  const int* dst = src + E;
  for (int i = tid; i < nodes; i += 256) cnt[i] = 0;
  __syncthreads();
  for (int e = tid; e < E; e += 256) atomicAdd(&cnt[dst[e]], 1);
  __syncthreads();
  int per = (nodes + 255) / 256;
  int s = 0;
  for (int k = 0; k < per; ++k) { int i = tid * per + k; if (i < nodes) s += cnt[i]; }
  bsum[tid] = s;
  __syncthreads();
  if (tid == 0) { int a = 0; for (int i = 0; i < 256; ++i) { int t = bsum[i]; bsum[i] = a; a += t; } }
  __syncthreads();
  s = bsum[tid];
  for (int k = 0; k < per; ++k) {
    int i = tid * per + k;
    if (i < nodes) { pos[i] = s; int t = cnt[i]; cnt[i] = s; s += t; }
  }
  __syncthreads();
  for (int i = tid; i < nodes; i += 256) off[(size_t)g * (nodes + 1) + i] = cnt[i];
  if (tid == 0) off[(size_t)g * (nodes + 1) + nodes] = E;
  for (int e = tid; e < E; e += 256) {
    int p = atomicAdd(&pos[dst[e]], 1);
    csr[(size_t)g * E + p] = src[e];
  }
}

// ---------------- prep for all 4 layers: pack W -> Bp2 sets + wvec dots ----------------
__global__ void k_prep_all(const float* __restrict__ txtW, const float* __restrict__ txtAs,
                           const float* __restrict__ txtAd,
                           const float* __restrict__ imgW, const float* __restrict__ imgAs,
                           const float* __restrict__ imgAd,
                           bf16* __restrict__ Bp2, float* __restrict__ wsrc4,
                           float* __restrict__ wdst4) {
  const int per = 320 * KP2 + 2 * H_ * D_;
  int gid = blockIdx.x * 256 + threadIdx.x;
  int s = gid / per;
  if (s >= 4) return;
  int idx = gid - s * per;
  const float* W   = (s < 2) ? txtW + (size_t)s * D_ * H_ * D_ : imgW + (size_t)(s - 2) * D_ * H_ * D_;
  const float* as_ = (s < 2) ? txtAs + s * H_ * D_ : imgAs + (s - 2) * H_ * D_;
  const float* ad_ = (s < 2) ? txtAd + s * H_ * D_ : imgAd + (s - 2) * H_ * D_;
  bf16* B = Bp2 + (size_t)s * 320 * KP2;
  if (idx < 320 * KP2) {
    int n = idx / KP2, k = idx - n * KP2;
    float v = 0.f;
    if (n < D_ && k < H_ * D_) {
      int h = k / D_, di = k - h * D_;
      v = W[(size_t)di * (H_ * D_) + h * D_ + n];
    }
    B[idx] = f2bf(v);
  } else {
    int r2 = idx - 320 * KP2;
    int sd = r2 / (H_ * D_);
    int r = r2 % (H_ * D_);
    int h = r / D_, d = r % D_;
    const float* att = (sd ? ad_ : as_) + h * D_;
    const float* Wp = W + (size_t)d * H_ * D_ + h * D_;
    float acc = 0.f;
    for (int e = 0; e < D_; ++e) acc += Wp[e] * att[e];
    (sd ? wdst4 : wsrc4)[s * H_ * D_ + h * D_ + d] = acc;
  }
}

// ---------------- phase0: token logits + softmax + c + u1 + c-row np-logit ----------------
__global__ __launch_bounds__(1024) void k_phase0(
    const float* __restrict__ t2, const float* __restrict__ score,
    const float* __restrict__ w1, const float* __restrict__ b1,
    const void* __restrict__ kpm, const int* __restrict__ mmode,
    const float* __restrict__ w2, const float* __restrict__ b2, const void* __restrict__ npm,
    float* __restrict__ c, float* __restrict__ u1, float* __restrict__ lg2) {
  __shared__ float pr[LL];
  __shared__ float cpart[16][304];
  __shared__ float upart[16][304];
  __shared__ float red[16];
  __shared__ float stat;
  int n = blockIdx.x, tid = threadIdx.x;
  int wave = tid >> 6, lane = tid & 63;
  int mode = mmode[0];
  float w1r[5];
#pragma unroll
  for (int k = 0; k < 5; ++k) { int d = lane + 64 * k; w1r[k] = (d < D_) ? w1[d] : 0.f; }
  const float* tb = t2 + (size_t)n * LL * D_;
  for (int r = 0; r < 64; ++r) {
    int l = wave * 64 + r;
    const float* tp = tb + (size_t)l * D_;
    float a = 0.f;
#pragma unroll
    for (int k = 0; k < 5; ++k) { int d = lane + 64 * k; if (d < D_) a += tp[d] * w1r[k]; }
#pragma unroll
    for (int o = 32; o; o >>= 1) a += __shfl_down(a, o);
    if (lane == 0) {
      float v = clamp_logit(a + b1[0]);
      if (read_mask(kpm, n * LL + l, mode)) v = -INFINITY;
      pr[l] = v;
    }
  }
  __syncthreads();
  float v = pr[tid];
  float m = v;
#pragma unroll
  for (int o = 1; o < 64; o <<= 1) m = fmaxf(m, __shfl_xor(m, o));
  if (lane == 0) red[wave] = m;
  __syncthreads();
  if (tid == 0) {
    float M = -INFINITY;
    for (int w = 0; w < 16; ++w) M = fmaxf(M, red[w]);
    if (!(M > -INFINITY && M < INFINITY)) M = 0.f;
    stat = M;
  }
  __syncthreads();
  float M = stat;
  float p = __expf(v - M);
  float s = p;
#pragma unroll
  for (int o = 1; o < 64; o <<= 1) s += __shfl_xor(s, o);
  if (lane == 0) red[wave] = s;
  __syncthreads();
  if (tid == 0) {
    float S = 0.f;
    for (int w = 0; w < 16; ++w) S += red[w];
    stat = (S > 0.f) ? 1.f / S : 0.f;
  }
  __syncthreads();
  pr[tid] = p * stat;
  __syncthreads();
  float aC[5] = {}, aU[5] = {};
  const float* sb = score + (size_t)n * LL * D_;
  for (int r = 0; r < 64; ++r) {
    int l = wave * 64 + r;
    float wgt = pr[l];
    const float* tp = tb + (size_t)l * D_;
    const float* sp = sb + (size_t)l * D_;
#pragma unroll
    for (int k = 0; k < 5; ++k) {
      int d = lane + 64 * k;
      if (d < D_) { float tv = tp[d]; aC[k] += tv * sp[d]; aU[k] += wgt * tv; }
    }
  }
  __syncthreads();   // pr reads done before reuse
#pragma unroll
  for (int k = 0; k < 5; ++k) {
    int d = lane + 64 * k;
    if (d < D_) { cpart[wave][d] = aC[k]; upart[wave][d] = aU[k]; }
  }
  __syncthreads();
  if (tid < D_) {
    float sC = 0.f, sU = 0.f;
    for (int w = 0; w < 16; ++w) { sC += cpart[w][tid]; sU += upart[w][tid]; }
    c[n * D_ + tid] = sC;
    u1[n * D_ + tid] = sU;
    pr[tid] = sC;       // cfin
  }
  __syncthreads();
  if (tid < 64) {
    float a = 0.f;
#pragma unroll
    for (int k = 0; k < 5; ++k) { int d = tid + 64 * k; if (d < D_) a += pr[d] * w2[d]; }
#pragma unroll
    for (int o = 32; o; o >>= 1) a += __shfl_down(a, o);
    if (tid == 0) {
      float vv = clamp_logit(a + b2[0]);
      if (read_mask(npm, n * (LL + 1) + LL, mode)) vv = -INFINITY;
      lg2[n * (LL + 1) + LL] = vv;
    }
  }
}

// ---------------- a_src/a_dst[row,h] = x[row,:] . wvec[h,:] ----------------
template <typename T>
__global__ void k_asrc(const T* __restrict__ x, const float* __restrict__ wsrc,
                       const float* __restrict__ wdst, float* __restrict__ a_src,
                       float* __restrict__ a_dst, int rows) {
  int row = blockIdx.x * blockDim.y + threadIdx.y;
  if (row >= rows) return;
  int lane = threadIdx.x;
  const T* xp = x + (size_t)row * D_;
  float xr[5];
#pragma unroll
  for (int i = 0; i < 5; ++i) { int d = lane + 64 * i; xr[i] = (d < D_) ? toF(xp[d]) : 0.f; }
#pragma unroll
  for (int hh = 0; hh < H_; ++hh) {
    float as = 0.f, ad = 0.f;
#pragma unroll
    for (int i = 0; i < 5; ++i) {
      int d = lane + 64 * i;
      if (d < D_) { as += xr[i] * wsrc[hh * D_ + d]; ad += xr[i] * wdst[hh * D_ + d]; }
    }
#pragma unroll
    for (int off = 32; off; off >>= 1) { as += __shfl_down(as, off); ad += __shfl_down(ad, off); }
    if (lane == 0) { a_src[(size_t)row * H_ + hh] = as; a_dst[(size_t)row * H_ + hh] = ad; }
  }
}

// ---------------- per-node aggregation (CSR) -> agg rows (KP2 bf16) ----------------
template <typename T>
__global__ __launch_bounds__(128) void k_agg(
    const T* __restrict__ x, const float* __restrict__ a_src, const float* __restrict__ a_dst,
    const int* __restrict__ csr, const int* __restrict__ off, int E, int nodes,
    int g_glob0, int per_graph, bf16* __restrict__ agg) {
  int g = blockIdx.x / nodes;
  int node = blockIdx.x % nodes;
  int gg = per_graph ? (g_glob0 + g) : 0;
  int tid = threadIdx.x;
  __shared__ int slist[MAXDEG];
  __shared__ float al[MAXDEG][H_];
  int o0 = off[(size_t)gg * (nodes + 1) + node];
  int deg = off[(size_t)gg * (nodes + 1) + node + 1] - o0;
  if (deg > MAXDEG) deg = MAXDEG;
  for (int i = tid; i < deg; i += 128) slist[i] = csr[(size_t)gg * E + o0 + i];
  __syncthreads();
  const float* adr = a_dst + ((size_t)g * nodes + node) * H_;
  for (int i = tid; i < deg * H_; i += 128) {
    int ei = i / H_, hh = i - ei * H_;
    float v = a_src[((size_t)g * nodes + slist[ei]) * H_ + hh] + adr[hh];
    al[ei][hh] = v > 0.f ? v : 0.2f * v;
  }
  __syncthreads();
  if (tid < H_) {
    float m = -INFINITY;
    for (int i = 0; i < deg; ++i) m = fmaxf(m, al[i][tid]);
    float s = 0.f;
    for (int i = 0; i < deg; ++i) { float p = __expf(al[i][tid] - m); al[i][tid] = p; s += p; }
    float inv = 1.f / (s + 1e-16f);
    for (int i = 0; i < deg; ++i) al[i][tid] *= inv;
  }
  __syncthreads();
  bf16* arow = agg + (size_t)(g * nodes + node) * KP2;
#pragma unroll
  for (int t = 0; t < 3; ++t) {
    int d = tid + t * 128;
    if (d < D_) {
      float o0v = 0.f, o1 = 0.f, o2 = 0.f, o3 = 0.f, o4 = 0.f;
      for (int i = 0; i < deg; ++i) {
        float xv = toF(x[((size_t)g * nodes + slist[i]) * D_ + d]);
        o0v += al[i][0] * xv; o1 += al[i][1] * xv; o2 += al[i][2] * xv;
        o3 += al[i][3] * xv; o4 += al[i][4] * xv;
      }
      arow[0 * D_ + d] = f2bf(o0v); arow[1 * D_ + d] = f2bf(o1);
      arow[2 * D_ + d] = f2bf(o2); arow[3 * D_ + d] = f2bf(o3);
      arow[4 * D_ + d] = f2bf(o4);
    }
  }
  if (tid < KP2 - H_ * D_) arow[H_ * D_ + tid] = f2bf(0.f);
}

// ---------------- pipelined MFMA GEMM (64x320) + fused LN (+ np logits) ----------------
__global__ __launch_bounds__(256) void k_gemm_ln(
    const bf16* __restrict__ agg, const bf16* __restrict__ Bp2,
    const float* __restrict__ bias, const float* __restrict__ lng, const float* __restrict__ lnb,
    const void* __restrict__ gmask, const int* __restrict__ mmode, int g_off, int nodes,
    int M, bf16* __restrict__ Xout,
    const float* __restrict__ w2, const float* __restrict__ b2, const void* __restrict__ npm,
    float* __restrict__ lg2) {
  __shared__ short As[64][40];
  __shared__ short Bs[320][40];
  int m0 = blockIdx.x * 64;
  int tid = threadIdx.x;
  int wave = tid >> 6, lane = tid & 63;
  int cl = lane & 15, q = lane >> 4;
  int wc = wave * 80;
  int am = tid >> 2, ak = (tid & 3) << 3;
  const bf16* gA = agg + (size_t)(m0 + am) * KP2 + ak;
  const bf16* gB[5];
  int bn[5], bk[5];
#pragma unroll
  for (int cc = 0; cc < 5; ++cc) {
    int cix = tid + cc * 256;
    bn[cc] = cix >> 2; bk[cc] = (cix & 3) << 3;
    gB[cc] = Bp2 + (size_t)bn[cc] * KP2 + bk[cc];
  }
  uint4 ra = *(const uint4*)gA;
  uint4 rb[5];
#pragma unroll
  for (int cc = 0; cc < 5; ++cc) rb[cc] = *(const uint4*)gB[cc];
  f32x4 acc[4][5] = {};
  for (int it = 0; it < 48; ++it) {
    __syncthreads();
    *(uint4*)&As[am][ak] = ra;
#pragma unroll
    for (int cc = 0; cc < 5; ++cc) *(uint4*)&Bs[bn[cc]][bk[cc]] = rb[cc];
    __syncthreads();
    if (it < 47) {
      gA += 32;
      ra = *(const uint4*)gA;
#pragma unroll
      for (int cc = 0; cc < 5; ++cc) { gB[cc] += 32; rb[cc] = *(const uint4*)gB[cc]; }
    }
    int ko = q << 3;
    short8 af[4];
#pragma unroll
    for (int i = 0; i < 4; ++i) af[i] = *(const short8*)&As[i * 16 + cl][ko];
#pragma unroll
    for (int j = 0; j < 5; ++j) {
      short8 bfr = *(const short8*)&Bs[wc + j * 16 + cl][ko];
#pragma unroll
      for (int i = 0; i < 4; ++i)
        acc[i][j] = __builtin_amdgcn_mfma_f32_16x16x32_bf16(af[i], bfr, acc[i][j], 0, 0, 0);
    }
  }
  __syncthreads();
  // epilogue: cross-wave LN (+ np logits). Reuse As as reduction scratch.
  float* sred = (float*)&As[0][0];   // [64][4]
  float* qred = sred + 256;          // [64][4]
  float* lred = qred + 256;          // [64][4]
  int mode = mmode[0];
#pragma unroll
  for (int i = 0; i < 4; ++i) {
#pragma unroll
    for (int r = 0; r < 4; ++r) {
      int lrow = i * 16 + q * 4 + r;
      int row = m0 + lrow;
      int mk = gmask ? read_mask(gmask, g_off + row / nodes, mode) : 0;
      float s = 0.f, sq = 0.f;
#pragma unroll
      for (int j = 0; j < 5; ++j) {
        int col = wc + j * 16 + cl;
        float v = 0.f;
        if (col < D_) {
          v = acc[i][j][r] * 0.2f + bias[col];
          if (mk) v = 0.f;
          v = fmaxf(v, 0.f);
        }
        s += v; sq += v * v;
      }
#pragma unroll
      for (int o = 1; o < 16; o <<= 1) { s += __shfl_xor(s, o); sq += __shfl_xor(sq, o); }
      if (cl == 0) { sred[lrow * 4 + wave] = s; qred[lrow * 4 + wave] = sq; }
    }
  }
  __syncthreads();
#pragma unroll
  for (int i = 0; i < 4; ++i) {
#pragma unroll
    for (int r = 0; r < 4; ++r) {
      int lrow = i * 16 + q * 4 + r;
      int row = m0 + lrow;
      float s = sred[lrow * 4 + 0] + sred[lrow * 4 + 1] + sred[lrow * 4 + 2] + sred[lrow * 4 + 3];
      float sq = qred[lrow * 4 + 0] + qred[lrow * 4 + 1] + qred[lrow * 4 + 2] + qred[lrow * 4 + 3];
      int mk = gmask ? read_mask(gmask, g_off + row / nodes, mode) : 0;
      float mu = s * (1.f / 300.f);
      float var = fmaxf(sq * (1.f / 300.f) - mu * mu, 0.f);
      float rstd = rsqrtf(var + 1e-5f);
      float ls = 0.f;
#pragma unroll
      for (int j = 0; j < 5; ++j) {
        int col = wc + j * 16 + cl;
        if (col < D_) {
          float v = acc[i][j][r] * 0.2f + bias[col];
          if (mk) v = 0.f;
          v = fmaxf(v, 0.f);
          float o2 = (v - mu) * rstd * lng[col] + lnb[col];
          Xout[(size_t)row * D_ + col] = f2bf(o2);
          if (w2) ls += o2 * w2[col];
        }
      }
      if (w2) {
#pragma unroll
        for (int o = 1; o < 16; o <<= 1) ls += __shfl_xor(ls, o);
        if (cl == 0) lred[lrow * 4 + wave] = ls;
      }
    }
  }
  if (w2) {
    __syncthreads();
    if (tid < 64) {
      int row = m0 + tid;
      float tot = lred[tid * 4 + 0] + lred[tid * 4 + 1] + lred[tid * 4 + 2] + lred[tid * 4 + 3];
      float v = clamp_logit(tot + b2[0]);
      int gl = row / nodes, l = row - gl * nodes;
      int g = g_off + gl;
      if (read_mask(npm, g * (nodes + 1) + l, mode)) v = -INFINITY;
      lg2[g * (nodes + 1) + l] = v;
    }
  }
}

// ---------------- final: pa_np softmax + u2 + output dots ----------------
__global__ __launch_bounds__(1024) void k_final(
    const float* __restrict__ lg2, const bf16* __restrict__ X, const float* __restrict__ c,
    const float* __restrict__ u1, const float* __restrict__ v2, const bf16* __restrict__ V,
    float* __restrict__ out) {
  __shared__ float p2[LL + 1];
  __shared__ float upart[16][304];
  __shared__ float u2c[304];
  __shared__ float u1l[304];
  __shared__ float red[16];
  __shared__ float stat;
  int n = blockIdx.x, tid = threadIdx.x;
  int wave = tid >> 6, lane = tid & 63;
  float v = lg2[n * (LL + 1) + tid];
  float vx = (tid == 0) ? lg2[n * (LL + 1) + LL] : -INFINITY;
  float m = fmaxf(v, vx);
#pragma unroll
  for (int o = 1; o < 64; o <<= 1) m = fmaxf(m, __shfl_xor(m, o));
  if (lane == 0) red[wave] = m;
  __syncthreads();
  if (tid == 0) {
    float M = -INFINITY;
    for (int w = 0; w < 16; ++w) M = fmaxf(M, red[w]);
    if (!(M > -INFINITY && M < INFINITY)) M = 0.f;
    stat = M;
  }
  __syncthreads();
  float M = stat;
  float p = __expf(v - M);
  float pL = (tid == 0) ? __expf(vx - M) : 0.f;
  float s = p + pL;
#pragma unroll
  for (int o = 1; o < 64; o <<= 1) s += __shfl_xor(s, o);
  if (lane == 0) red[wave] = s;
  __syncthreads();
  if (tid == 0) {
    float S = 0.f;
    for (int w = 0; w < 16; ++w) S += red[w];
    stat = (S > 0.f) ? 1.f / S : 0.f;
  }
  __syncthreads();
  float inv = stat;
  p2[tid] = p * inv;
  if (tid == 0) p2[LL] = pL * inv;
  __syncthreads();
  float aU[5] = {};
  const bf16* xb = X + (size_t)n * LL * D_;
  for (int r = 0; r < 64; ++r) {
    int l = wave * 64 + r;
    float wgt = p2[l];
    const bf16* xp = xb + (size_t)l * D_;
#pragma unroll
    for (int k = 0; k < 5; ++k) {
      int d = lane + 64 * k;
      if (d < D_) aU[k] += wgt * toF(xp[d]);
    }
  }
#pragma unroll
  for (int k = 0; k < 5; ++k) {
    int d = lane + 64 * k;
    if (d < D_) upart[wave][d] = aU[k];
  }
  __syncthreads();
  if (tid < D_) {
    float sU = 0.f;
    for (int w = 0; w < 16; ++w) sU += upart[w][tid];
    u2c[tid] = sU + p2[LL] * c[n * D_ + tid];
    u1l[tid] = u1[n * D_ + tid];
  }
  __syncthreads();
  const float scale = 0.05773502691896258f;  // 1/sqrt(300)
#pragma unroll
  for (int kk = 0; kk < 4; ++kk) {
    int k = wave * 4 + kk;
    const float* ap = v2 + ((size_t)n * KK + k) * D_;
    const bf16* bp = V + ((size_t)n * KK + k) * D_;
    float a1 = 0.f, a2 = 0.f;
#pragma unroll
    for (int t = 0; t < 5; ++t) {
      int d = lane + 64 * t;
      if (d < D_) { a1 += u1l[d] * ap[d]; a2 += u2c[d] * toF(bp[d]); }
    }
#pragma unroll
    for (int o = 32; o; o >>= 1) { a1 += __shfl_down(a1, o); a2 += __shfl_down(a2, o); }
    if (lane == 0) {
      out[(size_t)n * 2 * KK + k] = a1 * scale;
      out[(size_t)n * 2 * KK + KK + k] = a2 * scale;
    }
  }
}

extern "C" void kernel_launch(void* const* d_in, const int* in_sizes, int n_in,
                              void* d_out, int out_size, void* d_ws, size_t ws_size,
                              hipStream_t stream) {
  const float* t2    = (const float*)d_in[0];
  const float* v2    = (const float*)d_in[1];
  const float* score = (const float*)d_in[2];
  const int*   eidx  = (const int*)d_in[3];
  const void*  gmask = d_in[4];
  const void*  kpm   = d_in[5];
  const void*  npm   = d_in[6];
  const int*   iedge = (const int*)d_in[7];
  const float* txtW  = (const float*)d_in[8];
  const float* txtAs = (const float*)d_in[9];
  const float* txtAd = (const float*)d_in[10];
  const float* txtB  = (const float*)d_in[11];
  const float* imgW  = (const float*)d_in[12];
  const float* imgAs = (const float*)d_in[13];
  const float* imgAd = (const float*)d_in[14];
  const float* imgB  = (const float*)d_in[15];
  const float* w1    = (const float*)d_in[16];
  const float* b1    = (const float*)d_in[17];
  const float* w2    = (const float*)d_in[18];
  const float* b2    = (const float*)d_in[19];
  const float* lng   = (const float*)d_in[20];
  const float* lnb   = (const float*)d_in[21];
  float* out = (float*)d_out;

  char* ws = (char*)d_ws;
  size_t off = 0;
  auto alloc = [&](size_t bytes) -> char* {
    char* p = ws + off;
    off += (bytes + 511) & ~(size_t)511;
    return p;
  };
  int*   mmode = (int*)alloc(64);
  float* c     = (float*)alloc((size_t)NB * D_ * 4);
  float* u1    = (float*)alloc((size_t)NB * D_ * 4);
  float* lg2   = (float*)alloc((size_t)NB * (LL + 1) * 4);
  float* wsrc4 = (float*)alloc((size_t)4 * H_ * D_ * 4);
  float* wdst4 = (float*)alloc((size_t)4 * H_ * D_ * 4);
  float* asrc  = (float*)alloc((size_t)NB * LL * H_ * 4);
  float* adst  = (float*)alloc((size_t)NB * LL * H_ * 4);
  int* csrT    = (int*)alloc((size_t)NB * ETXT * 4);
  int* offT    = (int*)alloc((size_t)NB * (LL + 1) * 4);
  int* csrI    = (int*)alloc((size_t)EIMG * 4);
  int* offI    = (int*)alloc((size_t)(KK + 1) * 4);
  bf16* X   = (bf16*)alloc((size_t)NB * LL * D_ * 2);   // txt state, in-place across layers
  bf16* V   = (bf16*)alloc((size_t)NB * KK * D_ * 2);   // img state
  bf16* Bp2 = (bf16*)alloc((size_t)4 * 320 * KP2 * 2);  // 4 packed weight sets
  size_t havail = (ws_size > off) ? (ws_size - off) : 0;
  bf16* agg = (bf16*)(ws + off);
  size_t per_g_txt = (size_t)LL * KP2 * 2;
  int cg = (int)(havail / per_g_txt);
  if (cg < 1) cg = 1;
  if (cg > NB) cg = NB;

  dim3 b64x4(64, 4);
  int Mt = NB * LL, Mi = NB * KK;
  const int per_set = 320 * KP2 + 2 * H_ * D_;

  k_init<<<66, 256, 0, stream>>>((const unsigned int*)kpm, NB * LL / 4, mmode,
                                 eidx, iedge, csrT, offT, csrI, offI);
  k_prep_all<<<(4 * per_set + 255) / 256, 256, 0, stream>>>(
      txtW, txtAs, txtAd, imgW, imgAs, imgAd, Bp2, wsrc4, wdst4);
  k_phase0<<<NB, 1024, 0, stream>>>(t2, score, w1, b1, kpm, mmode, w2, b2, npm, c, u1, lg2);

  // text GAT layers (chunked over graphs), in-place on X
  for (int layer = 0; layer < 2; ++layer) {
    const bf16* Bset = Bp2 + (size_t)layer * 320 * KP2;
    const float* ws_ = wsrc4 + layer * H_ * D_;
    const float* wd_ = wdst4 + layer * H_ * D_;
    for (int g0 = 0; g0 < NB; g0 += cg) {
      int gs = (cg < NB - g0) ? cg : (NB - g0);
      int M = gs * LL;
      bf16* Xio = X + (size_t)g0 * LL * D_;
      if (layer == 0) {
        const float* Xin = t2 + (size_t)g0 * LL * D_;
        k_asrc<float><<<(M + 3) / 4, b64x4, 0, stream>>>(Xin, ws_, wd_, asrc, adst, M);
        k_agg<float><<<M, 128, 0, stream>>>(Xin, asrc, adst, csrT, offT, ETXT, LL, g0, 1, agg);
      } else {
        k_asrc<bf16><<<(M + 3) / 4, b64x4, 0, stream>>>(Xio, ws_, wd_, asrc, adst, M);
        k_agg<bf16><<<M, 128, 0, stream>>>(Xio, asrc, adst, csrT, offT, ETXT, LL, g0, 1, agg);
      }
      if (layer == 1)
        k_gemm_ln<<<M / 64, 256, 0, stream>>>(agg, Bset, txtB + D_, lng, lnb, gmask, mmode,
                                              g0, LL, M, Xio, w2, b2, npm, lg2);
      else
        k_gemm_ln<<<M / 64, 256, 0, stream>>>(agg, Bset, txtB, lng, lnb, gmask, mmode,
                                              g0, LL, M, Xio, nullptr, nullptr, nullptr, nullptr);
    }
  }

  // image GAT layers, in-place on V (agg region reused; 12.6 MB)
  for (int layer = 0; layer < 2; ++layer) {
    const bf16* Bset = Bp2 + (size_t)(2 + layer) * 320 * KP2;
    const float* ws_ = wsrc4 + (2 + layer) * H_ * D_;
    const float* wd_ = wdst4 + (2 + layer) * H_ * D_;
    if (layer == 0) {
      k_asrc<float><<<(Mi + 3) / 4, b64x4, 0, stream>>>(v2, ws_, wd_, asrc, adst, Mi);
      k_agg<float><<<Mi, 128, 0, stream>>>(v2, asrc, adst, csrI, offI, EIMG, KK, 0, 0, agg);
    } else {
      k_asrc<bf16><<<(Mi + 3) / 4, b64x4, 0, stream>>>(V, ws_, wd_, asrc, adst, Mi);
      k_agg<bf16><<<Mi, 128, 0, stream>>>(V, asrc, adst, csrI, offI, EIMG, KK, 0, 0, agg);
    }
    k_gemm_ln<<<Mi / 64, 256, 0, stream>>>(agg, Bset, imgB + layer * D_, lng, lnb,
                                           nullptr, mmode, 0, KK, Mi, V,
                                           nullptr, nullptr, nullptr, nullptr);
  }

  k_final<<<NB, 1024, 0, stream>>>(lg2, X, c, u1, v2, V, out);
}